// Round 14
// baseline (26.226 us; speedup 1.0000x reference)
//
#include <hip/hip_runtime.h>
#include <math.h>
#include <stdint.h>

#define N_AGENTS 2048
#define R_CAND   128
#define NUM_MODS 6
#define T_STEPS  30
#define B_BATCH  16

// out layout: [0]=cls_loss, [1]=reg_loss, [2..5761]=traj_eval(16,6,30,2), [5762]=num_cls, [5763]=num_reg

__global__ __launch_bounds__(256) void agent_kernel(
    const float* __restrict__ roi,      // [N*R,5]
    const float* __restrict__ anchor,   // [N*R,4]
    const float* __restrict__ ctrs,     // [N,2]
    const float* __restrict__ feats,    // [N,20,3]
    const float* __restrict__ gt,       // [N,T,2]
    const int* __restrict__ has,        // [N,T] bool -> int32
    const int* __restrict__ natgs,      // [B]
    float* __restrict__ out,
    float* __restrict__ part)           // [N,4]
{
    const int a   = blockIdx.x;
    const int tid = threadIdx.x;

    // Original candidate order throughout (no sort): NMS priority resolved at
    // pair-test time via (logit, idx); ballot-fixpoint == greedy NMS (unique fixpoint).
    __shared__ float4   s_goal[R_CAND];                 // (gx,gy,g2,g3)
    __shared__ float    s_logic[R_CAND];
    __shared__ float2   s_pos[R_CAND];                  // (gx,gy) for pair loop
    __shared__ float    s_d[R_CAND];                    // dist to gt endpoint
    __shared__ __align__(16) uint32_t s_col[R_CAND][4]; // 128-bit suppressor columns
    __shared__ float    s_gtrow[T_STEPS * 2];
    __shared__ int      s_has[T_STEPS];
    __shared__ int      s_natgs[B_BATCH];
    __shared__ float    s_coef[NUM_MODS][6];            // a0,a1,a2,b0,b1,b2

    // ---- A: loads (t<128 own one candidate) + prefetches + zero-init
    float ap0 = 0.f, ap1 = 0.f, ap2 = 0.f, ap3 = 0.f;   // live on lanes 0..5 only
    if (tid < NUM_MODS) {                                // issue EARLY: used in phase D
        ap0 = ctrs[(size_t)a * 2 + 0];
        ap1 = ctrs[(size_t)a * 2 + 1];
        ap2 = feats[((size_t)a * 20 + 19) * 3 + 0];
        ap3 = feats[((size_t)a * 20 + 19) * 3 + 1];
    }
    float lg = 0.0f, gx = 0.0f, gy = 0.0f;
    if (tid < R_CAND) {
        const float* rp  = roi + (size_t)(a * R_CAND + tid) * 5;
        const float4 anc = *reinterpret_cast<const float4*>(anchor + (size_t)(a * R_CAND + tid) * 4);
        lg = rp[0];
        gx = anc.x + rp[1];
        gy = anc.y + rp[2];
        s_logic[tid] = lg;
        s_goal[tid]  = make_float4(gx, gy, anc.z + rp[3], anc.w + rp[4]);
        s_pos[tid]   = make_float2(gx, gy);
        *reinterpret_cast<uint4*>(&s_col[tid][0]) = make_uint4(0u, 0u, 0u, 0u);
    } else if (tid < 128 + 60) {
        s_gtrow[tid - 128] = gt[(size_t)a * T_STEPS * 2 + (tid - 128)];
    } else if (tid >= 192 && tid < 192 + T_STEPS) {
        s_has[tid - 192] = has[(size_t)a * T_STEPS + (tid - 192)];
    } else if (tid >= 224 && tid < 224 + B_BATCH) {
        s_natgs[tid - 224] = natgs[tid - 224];
    }
    __syncthreads();

    // ---- C: balanced all-pairs suppression, ~32 iters/lane across 256 threads
    //      boxes 0.5x0.5: iou>0.5 <=> wx>0 && wx*wy>1/6, wx=0.5-|dx|
    {
        const int c = tid & 127, hf = tid >> 7;
        const float2 pt = (tid < 128) ? make_float2(gx, gy) : s_pos[c];
        if (hf == 0) s_d[c] = fabsf(pt.x - s_gtrow[(T_STEPS - 1) * 2]) +
                              fabsf(pt.y - s_gtrow[(T_STEPS - 1) * 2 + 1]);
        const float lgc = s_logic[c];
        const int dlo = hf ? 33 : 1;
        const int dhi = hf ? ((c < 64) ? 64 : 63) : 32;   // d=64 pair tested once (c<64)
        for (int d = dlo; d <= dhi; ++d) {
            const int p = (c + d) & (R_CAND - 1);
            const float2 pp = s_pos[p];
            const float wx = 0.5f - fabsf(pt.x - pp.x);
            const float wy = 0.5f - fabsf(pt.y - pp.y);
            if (wx > 0.0f && wx * wy > (1.0f / 6.0f)) {   // ~8 hits per agent total
                const float lgp = s_logic[p];
                const int p_wins = (lgp > lgc) || (lgp == lgc && p < c);
                const int sup  = p_wins ? c : p;          // suppressed candidate
                const int by   = p_wins ? p : c;          // suppressor
                atomicOr(&s_col[sup][by >> 5], 1u << (by & 31));
            }
        }
    }
    __syncthreads();

    // ---- D (wave 0): ballot-fixpoint NMS -> packed-u64 top-6 -> coefficients
    float my_slog = 0.0f; int my_win = 0;   // valid on lanes 0..5
    if (tid < 64) {
        const uint64_t cA0 = (uint64_t)s_col[tid][0]      | ((uint64_t)s_col[tid][1]      << 32);
        const uint64_t cA1 = (uint64_t)s_col[tid][2]      | ((uint64_t)s_col[tid][3]      << 32);
        const uint64_t cB0 = (uint64_t)s_col[tid + 64][0] | ((uint64_t)s_col[tid + 64][1] << 32);
        const uint64_t cB1 = (uint64_t)s_col[tid + 64][2] | ((uint64_t)s_col[tid + 64][3] << 32);
        uint64_t k0 = ~0ull, k1 = ~0ull;
        for (int it = 0; it < 200; ++it) {                  // fixpoint == greedy NMS
            const int slo = (((cA0 & k0) | (cA1 & k1)) != 0);
            const int shi = (((cB0 & k0) | (cB1 & k1)) != 0);
            const uint64_t n0 = ~__ballot(slo);
            const uint64_t n1 = ~__ballot(shi);
            if (n0 == k0 && n1 == k1) break;
            k0 = n0; k1 = n1;
        }
        const int kfall = (__popcll(k0) + __popcll(k1)) < NUM_MODS;
        const float d_lo = (kfall | (int)((k0 >> tid) & 1)) ? s_d[tid]      : INFINITY;
        const float d_hi = (kfall | (int)((k1 >> tid) & 1)) ? s_d[tid + 64] : INFINITY;
        // packed key: (float bits << 32) | idx — dist>=0 so bit order == numeric order;
        // embedded idx reproduces the stable (dist asc, idx asc) tie-break exactly.
        uint64_t lo = ((uint64_t)__float_as_uint(d_lo) << 32) | (uint32_t)tid;
        uint64_t hi = ((uint64_t)__float_as_uint(d_hi) << 32) | (uint32_t)(tid + 64);
        for (int m = 0; m < NUM_MODS; ++m) {
            uint64_t v = (lo < hi) ? lo : hi;
            for (int off = 32; off >= 1; off >>= 1) {
                const uint64_t o = __shfl_down(v, (unsigned)off, 64);
                v = (o < v) ? o : v;
            }
            v = __shfl(v, 0, 64);                           // broadcast winning key
            if (tid == m) my_win = (int)(uint32_t)(v & 0xffffffffu);
            if (lo == v) lo = ~0ull;                        // dedup (keys unique)
            if (hi == v) hi = ~0ull;
        }
        if (tid < NUM_MODS) {
            const float4 g = s_goal[my_win];
            my_slog = s_logic[my_win];
            const float a1c = (2.f * g.x * ap2 + 2.f * ap0 * ap2) / (2.f + ap2 - g.z);
            const float a0c = g.x - ap0 - a1c;
            const float b1c = (2.f * g.y * ap3 + 2.f * ap1 * ap3) / (2.f + ap3 - g.w);
            const float b0c = g.y - ap1 - b1c;
            s_coef[tid][0] = a0c; s_coef[tid][1] = a1c; s_coef[tid][2] = ap0;
            s_coef[tid][3] = b0c; s_coef[tid][4] = b1c; s_coef[tid][5] = ap1;
        }
    }
    __syncthreads();
    // (phase E deleted: trajectories evaluated on demand from s_coef,
    //  identical expression order -> bit-identical results; proven correct in r11)

    // ---- F (wave 0): losses  ||  G (wave 1): traj_eval gather; waves 2-3 done
    if (tid < 64) {
        float bv = -1e30f; int bt = tid;
        if (tid < T_STEPS) bv = (s_has[tid] ? 1.0f : 0.0f) + (0.1f * (float)tid) / (float)T_STEPS;
        for (int off = 16; off >= 1; off >>= 1) {
            const float ov = __shfl_down(bv, (unsigned)off, 32);
            const int   ot = __shfl_down(bt, (unsigned)off, 32);
            if (ov > bv || (ov == bv && ot < bt)) { bv = ov; bt = ot; }
        }
        const int   lt   = __shfl(bt, 0, 64);
        const float bmax = __shfl(bv, 0, 64);
        const int   mask = bmax > 1.0f;
        const float egx = s_gtrow[lt * 2 + 0], egy = s_gtrow[lt * 2 + 1];
        // mi = argmin over 6 modes: traj on demand at t=lt
        float md = 1e30f; int mm = tid;
        if (tid < NUM_MODS) {
            const float s1 = (float)lt / (float)(T_STEPS - 1);
            const float s2 = s1 * s1;
            const float tx = s_coef[tid][0] * s2 + s_coef[tid][1] * s1 + s_coef[tid][2];
            const float ty = s_coef[tid][3] * s2 + s_coef[tid][4] * s1 + s_coef[tid][5];
            const float dx = tx - egx, dy = ty - egy;
            md = sqrtf(dx * dx + dy * dy);
        }
        for (int off = 4; off >= 1; off >>= 1) {
            const float ov = __shfl_down(md, (unsigned)off, 8);
            const int   om = __shfl_down(mm, (unsigned)off, 8);
            if (ov < md || (ov == md && om < mm)) { md = ov; mm = om; }
        }
        const int mi = __shfl(mm, 0, 64);
        float cv = 0.0f;
        if (tid < NUM_MODS) {
            const float l = my_slog;
            const float g = (tid == mi) ? 1.0f : 0.0f;
            cv = fmaxf(l, 0.0f) - l * g + log1pf(expf(-fabsf(l)));
        }
        cv += __shfl_xor(cv, 4, 8); cv += __shfl_xor(cv, 2, 8); cv += __shfl_xor(cv, 1, 8);
        float rv = 0.0f;
        if (tid < 2 * T_STEPS) {
            const int t = tid >> 1, c = tid & 1;
            if (mask && s_has[t]) {
                const float s1 = (float)t / (float)(T_STEPS - 1);
                const float s2 = s1 * s1;
                const float tv = s_coef[mi][3 * c] * s2 + s_coef[mi][3 * c + 1] * s1 + s_coef[mi][3 * c + 2];
                const float diff = tv - s_gtrow[t * 2 + c];
                const float ad = fabsf(diff);
                rv = (ad < 1.0f) ? 0.5f * diff * diff : (ad - 0.5f);
            }
        }
        for (int off = 32; off >= 1; off >>= 1) rv += __shfl_xor(rv, (unsigned)off, 64);
        const int hv = (tid < T_STEPS) ? s_has[tid] : 0;
        const int nh = __popcll(__ballot(hv != 0));
        if (tid == 0) {
            *reinterpret_cast<float4*>(&part[(size_t)a * 4]) =
                make_float4(mask ? cv : 0.0f, rv, mask ? 1.0f : 0.0f, mask ? (float)nh : 0.0f);
        }
    } else if (tid < 128) {
        // gather (temp is NOT cumsum: [0, natgs[0], ..., natgs[14]]) — natgs from LDS
        const int p = tid - 64;
        for (int b = 0; b < B_BATCH; ++b) {
            const int target = (b == 0) ? 0 : s_natgs[b - 1];
            if (target == a) {
                for (int q = p; q < NUM_MODS * T_STEPS * 2; q += 64) {
                    const int m = q / 60, rem = q % 60;
                    const int t = rem >> 1, c = rem & 1;
                    const float s1 = (float)t / (float)(T_STEPS - 1);
                    const float s2 = s1 * s1;
                    const float tv = s_coef[m][3 * c] * s2 + s_coef[m][3 * c + 1] * s1 + s_coef[m][3 * c + 2];
                    out[2 + (size_t)b * NUM_MODS * T_STEPS * 2 + q] = tv;
                }
            }
        }
    }
}

__global__ __launch_bounds__(256) void reduce_kernel(
    const float4* __restrict__ part4, float* __restrict__ out)
{
    const int tid = threadIdx.x, lane = tid & 63, w = tid >> 6;
    __shared__ double sp[4][4];
    double c = 0, r = 0, n = 0, wv = 0;
    for (int a = tid; a < N_AGENTS; a += 256) {
        const float4 v = part4[a];
        c += (double)v.x; r += (double)v.y; n += (double)v.z; wv += (double)v.w;
    }
    for (int off = 32; off >= 1; off >>= 1) {
        c  += __shfl_down(c,  (unsigned)off, 64);
        r  += __shfl_down(r,  (unsigned)off, 64);
        n  += __shfl_down(n,  (unsigned)off, 64);
        wv += __shfl_down(wv, (unsigned)off, 64);
    }
    if (lane == 0) { sp[w][0] = c; sp[w][1] = r; sp[w][2] = n; sp[w][3] = wv; }
    __syncthreads();
    if (tid == 0) {
        out[0]    = (float)(sp[0][0] + sp[1][0] + sp[2][0] + sp[3][0]);
        out[1]    = (float)(sp[0][1] + sp[1][1] + sp[2][1] + sp[3][1]);
        out[5762] = (float)(sp[0][2] + sp[1][2] + sp[2][2] + sp[3][2]);
        out[5763] = (float)(sp[0][3] + sp[1][3] + sp[2][3] + sp[3][3]);
    }
}

extern "C" void kernel_launch(void* const* d_in, const int* in_sizes, int n_in,
                              void* d_out, int out_size, void* d_ws, size_t ws_size,
                              hipStream_t stream) {
    const float*   roi    = (const float*)d_in[0];
    const float*   anchor = (const float*)d_in[1];
    const float*   ctrs   = (const float*)d_in[2];
    const float*   feats  = (const float*)d_in[3];
    const float*   gt     = (const float*)d_in[4];
    const int*     has    = (const int*)d_in[5];
    const int*     natgs  = (const int*)d_in[6];
    float* out  = (float*)d_out;
    float* part = (float*)d_ws;   // 2048*4 floats = 32 KB

    agent_kernel<<<N_AGENTS, 256, 0, stream>>>(roi, anchor, ctrs, feats, gt, has, natgs, out, part);
    reduce_kernel<<<1, 256, 0, stream>>>((const float4*)part, out);
}

// Round 15
// 21.399 us; speedup vs baseline: 1.2255x; 1.2255x over previous
//
#include <hip/hip_runtime.h>
#include <math.h>
#include <stdint.h>

#define N_AGENTS 2048
#define R_CAND   128
#define NUM_MODS 6
#define T_STEPS  30
#define B_BATCH  16

// out layout: [0]=cls_loss, [1]=reg_loss, [2..5761]=traj_eval(16,6,30,2), [5762]=num_cls, [5763]=num_reg

__global__ __launch_bounds__(256) void agent_kernel(
    const float* __restrict__ roi,      // [N*R,5]
    const float* __restrict__ anchor,   // [N*R,4]
    const float* __restrict__ ctrs,     // [N,2]
    const float* __restrict__ feats,    // [N,20,3]
    const float* __restrict__ gt,       // [N,T,2]
    const int* __restrict__ has,        // [N,T] bool -> int32
    const int* __restrict__ natgs,      // [B]
    float* __restrict__ out,
    float* __restrict__ part)           // [N,4]
{
    const int a   = blockIdx.x;
    const int tid = threadIdx.x;

    // Original candidate order throughout (no sort): NMS priority resolved at
    // pair-test time via (logit, idx); ballot-fixpoint == greedy NMS (unique fixpoint).
    __shared__ float4   s_goal[R_CAND];                 // (gx,gy,g2,g3)
    __shared__ float    s_logic[R_CAND];
    __shared__ float2   s_pos[R_CAND];                  // (gx,gy) for pair loop
    __shared__ float    s_d[R_CAND];                    // dist to gt endpoint
    __shared__ __align__(16) uint32_t s_col[R_CAND][4]; // 128-bit suppressor columns
    __shared__ float    s_gtrow[T_STEPS * 2];
    __shared__ int      s_has[T_STEPS];
    __shared__ int      s_natgs[B_BATCH];
    __shared__ float    s_coef[NUM_MODS][6];
    __shared__ float    s_traj[NUM_MODS][T_STEPS][2];

    // ---- A: loads (t<128 own one candidate) + prefetches + zero-init
    float ap0 = 0.f, ap1 = 0.f, ap2 = 0.f, ap3 = 0.f;   // live on lanes 0..5 only
    if (tid < NUM_MODS) {                                // issue EARLY: used in phase D
        ap0 = ctrs[(size_t)a * 2 + 0];
        ap1 = ctrs[(size_t)a * 2 + 1];
        ap2 = feats[((size_t)a * 20 + 19) * 3 + 0];
        ap3 = feats[((size_t)a * 20 + 19) * 3 + 1];
    }
    float lg = 0.0f, gx = 0.0f, gy = 0.0f;
    if (tid < R_CAND) {
        const float* rp  = roi + (size_t)(a * R_CAND + tid) * 5;
        const float4 anc = *reinterpret_cast<const float4*>(anchor + (size_t)(a * R_CAND + tid) * 4);
        lg = rp[0];
        gx = anc.x + rp[1];
        gy = anc.y + rp[2];
        s_logic[tid] = lg;
        s_goal[tid]  = make_float4(gx, gy, anc.z + rp[3], anc.w + rp[4]);
        s_pos[tid]   = make_float2(gx, gy);
        *reinterpret_cast<uint4*>(&s_col[tid][0]) = make_uint4(0u, 0u, 0u, 0u);
    } else if (tid < 128 + 60) {
        s_gtrow[tid - 128] = gt[(size_t)a * T_STEPS * 2 + (tid - 128)];
    } else if (tid >= 192 && tid < 192 + T_STEPS) {
        s_has[tid - 192] = has[(size_t)a * T_STEPS + (tid - 192)];
    } else if (tid >= 224 && tid < 224 + B_BATCH) {
        s_natgs[tid - 224] = natgs[tid - 224];
    }
    __syncthreads();

    // ---- C: balanced all-pairs suppression, ~32 iters/lane across 256 threads
    //      boxes 0.5x0.5: iou>0.5 <=> wx>0 && wx*wy>1/6, wx=0.5-|dx|
    {
        const int c = tid & 127, hf = tid >> 7;
        const float2 pt = (tid < 128) ? make_float2(gx, gy) : s_pos[c];
        if (hf == 0) s_d[c] = fabsf(pt.x - s_gtrow[(T_STEPS - 1) * 2]) +
                              fabsf(pt.y - s_gtrow[(T_STEPS - 1) * 2 + 1]);
        const float lgc = s_logic[c];
        const int dlo = hf ? 33 : 1;
        const int dhi = hf ? ((c < 64) ? 64 : 63) : 32;   // d=64 pair tested once (c<64)
        for (int d = dlo; d <= dhi; ++d) {
            const int p = (c + d) & (R_CAND - 1);
            const float2 pp = s_pos[p];
            const float wx = 0.5f - fabsf(pt.x - pp.x);
            const float wy = 0.5f - fabsf(pt.y - pp.y);
            if (wx > 0.0f && wx * wy > (1.0f / 6.0f)) {   // ~8 hits per agent total
                const float lgp = s_logic[p];
                const int p_wins = (lgp > lgc) || (lgp == lgc && p < c);
                const int sup  = p_wins ? c : p;          // suppressed candidate
                const int by   = p_wins ? p : c;          // suppressor
                atomicOr(&s_col[sup][by >> 5], 1u << (by & 31));
            }
        }
    }
    __syncthreads();

    // ---- D (wave 0): ballot-fixpoint NMS -> packed-u64 top-6 -> coefficients
    float my_slog = 0.0f; int my_win = 0;   // valid on lanes 0..5
    if (tid < 64) {
        const uint64_t cA0 = (uint64_t)s_col[tid][0]      | ((uint64_t)s_col[tid][1]      << 32);
        const uint64_t cA1 = (uint64_t)s_col[tid][2]      | ((uint64_t)s_col[tid][3]      << 32);
        const uint64_t cB0 = (uint64_t)s_col[tid + 64][0] | ((uint64_t)s_col[tid + 64][1] << 32);
        const uint64_t cB1 = (uint64_t)s_col[tid + 64][2] | ((uint64_t)s_col[tid + 64][3] << 32);
        uint64_t k0 = ~0ull, k1 = ~0ull;
        for (int it = 0; it < 200; ++it) {                  // fixpoint == greedy NMS
            const int slo = (((cA0 & k0) | (cA1 & k1)) != 0);
            const int shi = (((cB0 & k0) | (cB1 & k1)) != 0);
            const uint64_t n0 = ~__ballot(slo);
            const uint64_t n1 = ~__ballot(shi);
            if (n0 == k0 && n1 == k1) break;
            k0 = n0; k1 = n1;
        }
        const int kfall = (__popcll(k0) + __popcll(k1)) < NUM_MODS;
        const float d_lo = (kfall | (int)((k0 >> tid) & 1)) ? s_d[tid]      : INFINITY;
        const float d_hi = (kfall | (int)((k1 >> tid) & 1)) ? s_d[tid + 64] : INFINITY;
        // packed key: (float bits << 32) | idx — dist>=0 so bit order == numeric order;
        // embedded idx reproduces the stable (dist asc, idx asc) tie-break exactly.
        uint64_t lo = ((uint64_t)__float_as_uint(d_lo) << 32) | (uint32_t)tid;
        uint64_t hi = ((uint64_t)__float_as_uint(d_hi) << 32) | (uint32_t)(tid + 64);
        for (int m = 0; m < NUM_MODS; ++m) {
            uint64_t v = (lo < hi) ? lo : hi;
            for (int off = 32; off >= 1; off >>= 1) {
                const uint64_t o = __shfl_down(v, (unsigned)off, 64);
                v = (o < v) ? o : v;
            }
            v = __shfl(v, 0, 64);                           // broadcast winning key
            if (tid == m) my_win = (int)(uint32_t)(v & 0xffffffffu);
            if (lo == v) lo = ~0ull;                        // dedup (keys unique)
            if (hi == v) hi = ~0ull;
        }
        if (tid < NUM_MODS) {
            const float4 g = s_goal[my_win];
            my_slog = s_logic[my_win];
            const float a1c = (2.f * g.x * ap2 + 2.f * ap0 * ap2) / (2.f + ap2 - g.z);
            const float a0c = g.x - ap0 - a1c;
            const float b1c = (2.f * g.y * ap3 + 2.f * ap1 * ap3) / (2.f + ap3 - g.w);
            const float b0c = g.y - ap1 - b1c;
            s_coef[tid][0] = a0c; s_coef[tid][1] = a1c; s_coef[tid][2] = ap0;
            s_coef[tid][3] = b0c; s_coef[tid][4] = b1c; s_coef[tid][5] = ap1;
        }
    }
    __syncthreads();

    // ---- E: trajectories (180 elems over 256 threads) — materialize ONCE
    //      (r14 bisection: on-demand eval in F/G costs +4.8 µs; keep this phase)
    if (tid < NUM_MODS * T_STEPS) {
        const int m = tid / T_STEPS, t = tid % T_STEPS;
        const float s1 = (float)t / (float)(T_STEPS - 1);
        const float s2 = s1 * s1;
        s_traj[m][t][0] = s_coef[m][0] * s2 + s_coef[m][1] * s1 + s_coef[m][2];
        s_traj[m][t][1] = s_coef[m][3] * s2 + s_coef[m][4] * s1 + s_coef[m][5];
    }
    __syncthreads();

    // ---- F (wave 0): losses  ||  G (wave 1): traj_eval gather; waves 2-3 done
    if (tid < 64) {
        float bv = -1e30f; int bt = tid;
        if (tid < T_STEPS) bv = (s_has[tid] ? 1.0f : 0.0f) + (0.1f * (float)tid) / (float)T_STEPS;
        for (int off = 16; off >= 1; off >>= 1) {
            const float ov = __shfl_down(bv, (unsigned)off, 32);
            const int   ot = __shfl_down(bt, (unsigned)off, 32);
            if (ov > bv || (ov == bv && ot < bt)) { bv = ov; bt = ot; }
        }
        const int   lt   = __shfl(bt, 0, 64);
        const float bmax = __shfl(bv, 0, 64);
        const int   mask = bmax > 1.0f;
        const float egx = s_gtrow[lt * 2 + 0], egy = s_gtrow[lt * 2 + 1];
        float md = 1e30f; int mm = tid;
        if (tid < NUM_MODS) {
            const float dx = s_traj[tid][lt][0] - egx;
            const float dy = s_traj[tid][lt][1] - egy;
            md = sqrtf(dx * dx + dy * dy);
        }
        for (int off = 4; off >= 1; off >>= 1) {
            const float ov = __shfl_down(md, (unsigned)off, 8);
            const int   om = __shfl_down(mm, (unsigned)off, 8);
            if (ov < md || (ov == md && om < mm)) { md = ov; mm = om; }
        }
        const int mi = __shfl(mm, 0, 64);
        float cv = 0.0f;
        if (tid < NUM_MODS) {
            const float l = my_slog;
            const float g = (tid == mi) ? 1.0f : 0.0f;
            cv = fmaxf(l, 0.0f) - l * g + log1pf(expf(-fabsf(l)));
        }
        cv += __shfl_xor(cv, 4, 8); cv += __shfl_xor(cv, 2, 8); cv += __shfl_xor(cv, 1, 8);
        float rv = 0.0f;
        if (tid < 2 * T_STEPS) {
            const int t = tid >> 1, c = tid & 1;
            if (mask && s_has[t]) {
                const float diff = s_traj[mi][t][c] - s_gtrow[t * 2 + c];
                const float ad = fabsf(diff);
                rv = (ad < 1.0f) ? 0.5f * diff * diff : (ad - 0.5f);
            }
        }
        for (int off = 32; off >= 1; off >>= 1) rv += __shfl_xor(rv, (unsigned)off, 64);
        const int hv = (tid < T_STEPS) ? s_has[tid] : 0;
        const int nh = __popcll(__ballot(hv != 0));
        if (tid == 0) {
            *reinterpret_cast<float4*>(&part[(size_t)a * 4]) =
                make_float4(mask ? cv : 0.0f, rv, mask ? 1.0f : 0.0f, mask ? (float)nh : 0.0f);
        }
    } else if (tid < 128) {
        // gather (temp is NOT cumsum: [0, natgs[0], ..., natgs[14]]) — natgs from LDS
        const float* tp = &s_traj[0][0][0];
        const int p = tid - 64;
        for (int b = 0; b < B_BATCH; ++b) {
            const int target = (b == 0) ? 0 : s_natgs[b - 1];
            if (target == a) {
                for (int q = p; q < NUM_MODS * T_STEPS * 2; q += 64)
                    out[2 + (size_t)b * NUM_MODS * T_STEPS * 2 + q] = tp[q];
            }
        }
    }
}

__global__ __launch_bounds__(256) void reduce_kernel(
    const float4* __restrict__ part4, float* __restrict__ out)
{
    const int tid = threadIdx.x, lane = tid & 63, w = tid >> 6;
    __shared__ double sp[4][4];
    double c = 0, r = 0, n = 0, wv = 0;
    for (int a = tid; a < N_AGENTS; a += 256) {
        const float4 v = part4[a];
        c += (double)v.x; r += (double)v.y; n += (double)v.z; wv += (double)v.w;
    }
    for (int off = 32; off >= 1; off >>= 1) {
        c  += __shfl_down(c,  (unsigned)off, 64);
        r  += __shfl_down(r,  (unsigned)off, 64);
        n  += __shfl_down(n,  (unsigned)off, 64);
        wv += __shfl_down(wv, (unsigned)off, 64);
    }
    if (lane == 0) { sp[w][0] = c; sp[w][1] = r; sp[w][2] = n; sp[w][3] = wv; }
    __syncthreads();
    if (tid == 0) {
        out[0]    = (float)(sp[0][0] + sp[1][0] + sp[2][0] + sp[3][0]);
        out[1]    = (float)(sp[0][1] + sp[1][1] + sp[2][1] + sp[3][1]);
        out[5762] = (float)(sp[0][2] + sp[1][2] + sp[2][2] + sp[3][2]);
        out[5763] = (float)(sp[0][3] + sp[1][3] + sp[2][3] + sp[3][3]);
    }
}

extern "C" void kernel_launch(void* const* d_in, const int* in_sizes, int n_in,
                              void* d_out, int out_size, void* d_ws, size_t ws_size,
                              hipStream_t stream) {
    const float*   roi    = (const float*)d_in[0];
    const float*   anchor = (const float*)d_in[1];
    const float*   ctrs   = (const float*)d_in[2];
    const float*   feats  = (const float*)d_in[3];
    const float*   gt     = (const float*)d_in[4];
    const int*     has    = (const int*)d_in[5];
    const int*     natgs  = (const int*)d_in[6];
    float* out  = (float*)d_out;
    float* part = (float*)d_ws;   // 2048*4 floats = 32 KB

    agent_kernel<<<N_AGENTS, 256, 0, stream>>>(roi, anchor, ctrs, feats, gt, has, natgs, out, part);
    reduce_kernel<<<1, 256, 0, stream>>>((const float4*)part, out);
}